// Round 7
// baseline (678.299 us; speedup 1.0000x reference)
//
#include <hip/hip_runtime.h>
#include <stdint.h>

#define N_NODES  (1u << 20)      // 1048576
#define N_EDGES  (1u << 24)      // 16777216
#define N_GRAPHS 64
#define CHUNK    (N_NODES / N_GRAPHS)  // 16384
#define K_HOPS   4

#define NBUCKET  1024            // column buckets
#define CPB      1024            // cols per bucket
#define CAP      18432           // slots per bucket region (λ=16384, +16σ)

#define NBLK_SS  512             // scatter-sort blocks
#define TB_SS    1024            // scatter-sort threads
#define EPT      32              // edges per thread
#define EPB_SS   (TB_SS * EPT)   // 32768 edges per block

// ---------------------------------------------------------------------------
// Edge dtype detection: int64 little-endian with values < 2^20 has all-zero
// odd u32 words; int32 has random indices there. flag[0]=1 -> int64.
__global__ void detect_kernel(const uint32_t* __restrict__ ei, int* __restrict__ flag) {
    __shared__ int any_nz;
    if (threadIdx.x == 0) any_nz = 0;
    __syncthreads();
    int nz = 0;
    for (int i = threadIdx.x; i < 32768; i += blockDim.x)
        nz |= (ei[2 * i + 1] != 0u);
    if (nz) atomicOr(&any_nz, 1);
    __syncthreads();
    if (threadIdx.x == 0) flag[0] = any_nz ? 0 : 1;
}

__global__ void zero_int_kernel(int* __restrict__ p) {
    int i = blockIdx.x * blockDim.x + threadIdx.x;
    p[i] = 0;
}

// ---------------------------------------------------------------------------
// Per-block LDS counting sort by bucket, then coalesced run write-out.
__global__ __launch_bounds__(TB_SS, 4)
void scatter_sort_kernel(const void* __restrict__ ei, const int* __restrict__ flag,
                         int* __restrict__ cursor, uint32_t* __restrict__ packed) {
    __shared__ uint32_t sorted[EPB_SS];   // 128 KB
    __shared__ int h[NBUCKET];            // 4 KB
    __shared__ int o[NBUCKET];            // 4 KB (scan, then bumped by scatter)
    __shared__ int ostart[NBUCKET];       // 4 KB (stable run starts)
    __shared__ int gbase[NBUCKET];        // 4 KB
    int blk = blockIdx.x, tid = threadIdx.x;
    h[tid] = 0;
    __syncthreads();
    size_t base = (size_t)blk * EPB_SS;
    int is64 = flag[0];
    uint32_t c_[EPT];

    // Phase A: load cols, histogram buckets.
    if (is64) {
        const unsigned long long* cp = (const unsigned long long*)ei + N_EDGES + base;
        #pragma unroll
        for (int it = 0; it < EPT / 4; ++it) {
            size_t i = (size_t)it * (TB_SS * 4) + (size_t)tid * 4;
            ulonglong2 a = *(const ulonglong2*)(cp + i);
            ulonglong2 b2 = *(const ulonglong2*)(cp + i + 2);
            c_[it * 4 + 0] = (uint32_t)a.x;  c_[it * 4 + 1] = (uint32_t)a.y;
            c_[it * 4 + 2] = (uint32_t)b2.x; c_[it * 4 + 3] = (uint32_t)b2.y;
            atomicAdd(&h[c_[it * 4 + 0] >> 10], 1);
            atomicAdd(&h[c_[it * 4 + 1] >> 10], 1);
            atomicAdd(&h[c_[it * 4 + 2] >> 10], 1);
            atomicAdd(&h[c_[it * 4 + 3] >> 10], 1);
        }
    } else {
        const uint32_t* cp = (const uint32_t*)ei + N_EDGES + base;
        #pragma unroll
        for (int it = 0; it < EPT / 4; ++it) {
            size_t i = (size_t)it * (TB_SS * 4) + (size_t)tid * 4;
            uint4 a = *(const uint4*)(cp + i);
            c_[it * 4 + 0] = a.x; c_[it * 4 + 1] = a.y;
            c_[it * 4 + 2] = a.z; c_[it * 4 + 3] = a.w;
            atomicAdd(&h[a.x >> 10], 1);
            atomicAdd(&h[a.y >> 10], 1);
            atomicAdd(&h[a.z >> 10], 1);
            atomicAdd(&h[a.w >> 10], 1);
        }
    }
    __syncthreads();

    // Phase B: wave 0 exclusive-scans h[1024] -> o/ostart.
    if (tid < 64) {
        int b16 = tid * 16;
        int s = 0;
        #pragma unroll
        for (int j = 0; j < 16; ++j) s += h[b16 + j];
        int v = s;
        #pragma unroll
        for (int off = 1; off < 64; off <<= 1) {
            int up = __shfl_up(v, off, 64);
            if (tid >= off) v += up;
        }
        int run = v - s;  // exclusive
        #pragma unroll
        for (int j = 0; j < 16; ++j) {
            o[b16 + j] = run;
            ostart[b16 + j] = run;
            run += h[b16 + j];
        }
    }
    __syncthreads();

    // Per-bucket global reserve (1 atomic per bucket per block).
    gbase[tid] = atomicAdd(&cursor[tid], h[tid]);

    // Phase C: load rows, scatter packed entries into LDS sorted buffer.
    if (is64) {
        const unsigned long long* rp = (const unsigned long long*)ei + base;
        #pragma unroll
        for (int it = 0; it < EPT / 4; ++it) {
            size_t i = (size_t)it * (TB_SS * 4) + (size_t)tid * 4;
            ulonglong2 a = *(const ulonglong2*)(rp + i);
            ulonglong2 b2 = *(const ulonglong2*)(rp + i + 2);
            uint32_t r0 = (uint32_t)a.x, r1 = (uint32_t)a.y;
            uint32_t r2 = (uint32_t)b2.x, r3 = (uint32_t)b2.y;
            { uint32_t c = c_[it * 4 + 0]; int pos = atomicAdd(&o[c >> 10], 1); sorted[pos] = (r0 << 10) | (c & 1023u); }
            { uint32_t c = c_[it * 4 + 1]; int pos = atomicAdd(&o[c >> 10], 1); sorted[pos] = (r1 << 10) | (c & 1023u); }
            { uint32_t c = c_[it * 4 + 2]; int pos = atomicAdd(&o[c >> 10], 1); sorted[pos] = (r2 << 10) | (c & 1023u); }
            { uint32_t c = c_[it * 4 + 3]; int pos = atomicAdd(&o[c >> 10], 1); sorted[pos] = (r3 << 10) | (c & 1023u); }
        }
    } else {
        const uint32_t* rp = (const uint32_t*)ei + base;
        #pragma unroll
        for (int it = 0; it < EPT / 4; ++it) {
            size_t i = (size_t)it * (TB_SS * 4) + (size_t)tid * 4;
            uint4 a = *(const uint4*)(rp + i);
            { uint32_t c = c_[it * 4 + 0]; int pos = atomicAdd(&o[c >> 10], 1); sorted[pos] = (a.x << 10) | (c & 1023u); }
            { uint32_t c = c_[it * 4 + 1]; int pos = atomicAdd(&o[c >> 10], 1); sorted[pos] = (a.y << 10) | (c & 1023u); }
            { uint32_t c = c_[it * 4 + 2]; int pos = atomicAdd(&o[c >> 10], 1); sorted[pos] = (a.z << 10) | (c & 1023u); }
            { uint32_t c = c_[it * 4 + 3]; int pos = atomicAdd(&o[c >> 10], 1); sorted[pos] = (a.w << 10) | (c & 1023u); }
        }
    }
    __syncthreads();

    // Phase D: write-out. Wave w copies buckets [w*64, w*64+64); runs contiguous.
    int wave = tid >> 6, lane = tid & 63;
    for (int k = 0; k < NBUCKET / 16; ++k) {
        int b = wave * (NBUCKET / 16) + k;
        int st = ostart[b];
        int len = o[b] - st;
        int gb = gbase[b];
        if (gb + len > CAP) len = CAP - gb > 0 ? CAP - gb : 0;
        uint32_t* dst = packed + (size_t)b * CAP + gb;
        for (int j = lane; j < len; j += 64)
            dst[j] = sorted[st + j];
    }
}

// ---------------------------------------------------------------------------
// Per-bucket degree -> dinv, fused with z0 = dinv * x. 2-gen pipelined loads.
__global__ __launch_bounds__(512)
void degdinv_kernel(const uint32_t* __restrict__ packed, const int* __restrict__ cursor,
                    const float* __restrict__ x,
                    float* __restrict__ dinv, float* __restrict__ z) {
    __shared__ int h[CPB];
    int b = blockIdx.x, tid = threadIdx.x;
    for (int l = tid; l < CPB; l += 512) h[l] = 0;
    __syncthreads();
    int cnt = cursor[b]; if (cnt > CAP) cnt = CAP;
    const uint32_t* seg = packed + (size_t)b * CAP;
    const uint4* s4 = (const uint4*)seg;
    int nq = cnt >> 2;
    int ns = nq >> 10;  // stages of 1024 uint4 (4096 edges)

    uint4 c0A, c0B, c1A, c1B;
    if (ns >= 1) { c0A = s4[tid]; c0B = s4[tid + 512]; }
    for (int it = 0; it < ns; ++it) {
        if (it + 1 < ns) {
            c1A = s4[(it + 1) * 1024 + tid];
            c1B = s4[(it + 1) * 1024 + 512 + tid];
        }
        atomicAdd(&h[c0A.x & 1023u], 1); atomicAdd(&h[c0A.y & 1023u], 1);
        atomicAdd(&h[c0A.z & 1023u], 1); atomicAdd(&h[c0A.w & 1023u], 1);
        atomicAdd(&h[c0B.x & 1023u], 1); atomicAdd(&h[c0B.y & 1023u], 1);
        atomicAdd(&h[c0B.z & 1023u], 1); atomicAdd(&h[c0B.w & 1023u], 1);
        c0A = c1A; c0B = c1B;
    }
    for (int g = ns * 1024 + tid; g < nq; g += 512) {
        uint4 v = s4[g];
        atomicAdd(&h[v.x & 1023u], 1);
        atomicAdd(&h[v.y & 1023u], 1);
        atomicAdd(&h[v.z & 1023u], 1);
        atomicAdd(&h[v.w & 1023u], 1);
    }
    int t = nq * 4 + tid;
    if (t < cnt) atomicAdd(&h[seg[t] & 1023u], 1);
    __syncthreads();
    for (int l = tid; l < CPB; l += 512) {
        int v = b * CPB + l;
        float d = (float)(1.0 / sqrt((double)(h[l] + 1)));  // +1 self loop
        dinv[v] = d;
        z[v] = d * x[v];
    }
}

// ---------------------------------------------------------------------------
// Bucketed hop, 3-generation software pipeline (loop-carried so the compiler
// cannot collapse it): iter it issues idx loads for stage it+2, z-gathers for
// stage it+1, and consumes stage it. ~18 outstanding loads per thread.
__global__ __launch_bounds__(512, 4)
void hop_kernel(const uint32_t* __restrict__ packed, const int* __restrict__ cursor,
                const float* __restrict__ z, const float* __restrict__ dinv,
                float* __restrict__ out, int mode) {
    __shared__ float facc[CPB];
    int b = blockIdx.x, tid = threadIdx.x;
    for (int l = tid; l < CPB; l += 512) facc[l] = 0.0f;
    __syncthreads();
    int cnt = cursor[b]; if (cnt > CAP) cnt = CAP;
    const uint32_t* seg = packed + (size_t)b * CAP;
    const uint4* s4 = (const uint4*)seg;
    int nq = cnt >> 2;
    int ns = nq >> 10;  // stages of 1024 uint4 (4096 edges/block-stage)

    uint4 i0A, i0B, i1A, i1B, i2A, i2B;
    float g0_0, g0_1, g0_2, g0_3, g0_4, g0_5, g0_6, g0_7;
    float g1_0, g1_1, g1_2, g1_3, g1_4, g1_5, g1_6, g1_7;
    if (ns >= 1) { i0A = s4[tid]; i0B = s4[tid + 512]; }
    if (ns >= 2) { i1A = s4[1024 + tid]; i1B = s4[1024 + 512 + tid]; }
    if (ns >= 1) {
        g0_0 = z[i0A.x >> 10]; g0_1 = z[i0A.y >> 10];
        g0_2 = z[i0A.z >> 10]; g0_3 = z[i0A.w >> 10];
        g0_4 = z[i0B.x >> 10]; g0_5 = z[i0B.y >> 10];
        g0_6 = z[i0B.z >> 10]; g0_7 = z[i0B.w >> 10];
    }
    for (int it = 0; it + 1 < ns; ++it) {
        if (it + 2 < ns) {
            i2A = s4[(it + 2) * 1024 + tid];
            i2B = s4[(it + 2) * 1024 + 512 + tid];
        }
        g1_0 = z[i1A.x >> 10]; g1_1 = z[i1A.y >> 10];
        g1_2 = z[i1A.z >> 10]; g1_3 = z[i1A.w >> 10];
        g1_4 = z[i1B.x >> 10]; g1_5 = z[i1B.y >> 10];
        g1_6 = z[i1B.z >> 10]; g1_7 = z[i1B.w >> 10];
        atomicAdd(&facc[i0A.x & 1023u], g0_0); atomicAdd(&facc[i0A.y & 1023u], g0_1);
        atomicAdd(&facc[i0A.z & 1023u], g0_2); atomicAdd(&facc[i0A.w & 1023u], g0_3);
        atomicAdd(&facc[i0B.x & 1023u], g0_4); atomicAdd(&facc[i0B.y & 1023u], g0_5);
        atomicAdd(&facc[i0B.z & 1023u], g0_6); atomicAdd(&facc[i0B.w & 1023u], g0_7);
        i0A = i1A; i0B = i1B; i1A = i2A; i1B = i2B;
        g0_0 = g1_0; g0_1 = g1_1; g0_2 = g1_2; g0_3 = g1_3;
        g0_4 = g1_4; g0_5 = g1_5; g0_6 = g1_6; g0_7 = g1_7;
    }
    if (ns >= 1) {
        atomicAdd(&facc[i0A.x & 1023u], g0_0); atomicAdd(&facc[i0A.y & 1023u], g0_1);
        atomicAdd(&facc[i0A.z & 1023u], g0_2); atomicAdd(&facc[i0A.w & 1023u], g0_3);
        atomicAdd(&facc[i0B.x & 1023u], g0_4); atomicAdd(&facc[i0B.y & 1023u], g0_5);
        atomicAdd(&facc[i0B.z & 1023u], g0_6); atomicAdd(&facc[i0B.w & 1023u], g0_7);
    }
    for (int g = ns * 1024 + tid; g < nq; g += 512) {
        uint4 v = s4[g];
        float q0 = z[v.x >> 10], q1 = z[v.y >> 10], q2 = z[v.z >> 10], q3 = z[v.w >> 10];
        atomicAdd(&facc[v.x & 1023u], q0);
        atomicAdd(&facc[v.y & 1023u], q1);
        atomicAdd(&facc[v.z & 1023u], q2);
        atomicAdd(&facc[v.w & 1023u], q3);
    }
    int t = nq * 4 + tid;
    if (t < cnt) { uint32_t p = seg[t]; atomicAdd(&facc[p & 1023u], z[p >> 10]); }
    __syncthreads();
    for (int l = tid; l < CPB; l += 512) {
        int v = b * CPB + l;
        float tt = z[v] + facc[l];
        float d = dinv[v];
        out[v] = mode ? d * d * tt : d * tt;
    }
}

// out[g] = W * mean_{chunk g}(xf) + b
__global__ void pool_kernel(const float* __restrict__ xf,
                            const float* __restrict__ W, const float* __restrict__ b,
                            float* __restrict__ out) {
    __shared__ double sdata[256];
    int g = blockIdx.x;
    int base = g * CHUNK;
    double s = 0.0;
    for (int i = threadIdx.x; i < CHUNK; i += 256) s += (double)xf[base + i];
    sdata[threadIdx.x] = s;
    __syncthreads();
    for (int off = 128; off > 0; off >>= 1) {
        if (threadIdx.x < off) sdata[threadIdx.x] += sdata[threadIdx.x + off];
        __syncthreads();
    }
    if (threadIdx.x == 0)
        out[g] = (float)((double)W[0] * (sdata[0] / (double)CHUNK) + (double)b[0]);
}

// ---------------- fallback (push, atomics) for small ws ---------------------
__device__ __forceinline__ int load_idx(const void* ei, int is64, size_t pos) {
    if (is64) return (int)((const unsigned long long*)ei)[pos];
    return ((const int*)ei)[pos];
}

__global__ void count_kernel(const void* __restrict__ ei, const int* __restrict__ flag,
                             int* __restrict__ deg) {
    int e = blockIdx.x * blockDim.x + threadIdx.x;
    int c = load_idx(ei, flag[0], (size_t)N_EDGES + (size_t)e);
    atomicAdd(&deg[c], 1);
}

__global__ void dinv_kernel(const int* __restrict__ deg, float* __restrict__ dinv) {
    int v = blockIdx.x * blockDim.x + threadIdx.x;
    dinv[v] = (float)(1.0 / sqrt((double)(deg[v] + 1)));
}

__global__ void prep_first2_kernel(const float* __restrict__ x, const float* __restrict__ dinv,
                                   float* __restrict__ z, float* __restrict__ acc) {
    int v = blockIdx.x * blockDim.x + threadIdx.x;
    float t = dinv[v] * x[v];
    z[v] = t;
    acc[v] = t;
}

__global__ void prep_mid_kernel(const float* __restrict__ dinv,
                                float* __restrict__ z, float* __restrict__ acc) {
    int v = blockIdx.x * blockDim.x + threadIdx.x;
    float d = dinv[v];
    float t = d * d * acc[v];
    z[v] = t;
    acc[v] = t;
}

__global__ void push_kernel(const void* __restrict__ ei, const int* __restrict__ flag,
                            const float* __restrict__ z, float* __restrict__ acc) {
    int e = blockIdx.x * blockDim.x + threadIdx.x;
    int is64 = flag[0];
    int r, c;
    if (is64) {
        const unsigned long long* p = (const unsigned long long*)ei;
        r = (int)p[e];
        c = (int)p[(size_t)N_EDGES + (size_t)e];
    } else {
        const int* p = (const int*)ei;
        r = p[e];
        c = p[(size_t)N_EDGES + (size_t)e];
    }
    __hip_atomic_fetch_add(&acc[c], z[r], __ATOMIC_RELAXED, __HIP_MEMORY_SCOPE_AGENT);
}

__global__ void final_scale_kernel(const float* __restrict__ dinv,
                                   const float* __restrict__ acc, float* __restrict__ xf) {
    int v = blockIdx.x * blockDim.x + threadIdx.x;
    xf[v] = dinv[v] * acc[v];
}

extern "C" void kernel_launch(void* const* d_in, const int* in_sizes, int n_in,
                              void* d_out, int out_size, void* d_ws, size_t ws_size,
                              hipStream_t stream) {
    const float* x = (const float*)d_in[0];
    const void*  ei = d_in[1];
    const float* W = (const float*)d_in[2];
    const float* b = (const float*)d_in[3];
    float* out = (float*)d_out;

    char* ws = (char*)d_ws;
    const size_t MB4 = 4ull << 20;
    size_t off_flag   = 0;                                // 256 B
    size_t off_cursor = 256;                              // 4 KB
    size_t off_dinv   = off_cursor + NBUCKET * 4;         // 4 MB
    size_t off_za     = off_dinv + MB4;                   // 4 MB
    size_t off_zb     = off_za + MB4;                     // 4 MB
    size_t off_packed = off_zb + MB4;                     // 72 MB
    size_t needed     = off_packed + (size_t)NBUCKET * CAP * 4;

    const int TB = 256;

    if (ws_size >= needed) {
        int*      flag   = (int*)(ws + off_flag);
        int*      cursor = (int*)(ws + off_cursor);
        float*    dinv   = (float*)(ws + off_dinv);
        float*    za     = (float*)(ws + off_za);
        float*    zb     = (float*)(ws + off_zb);
        uint32_t* packed = (uint32_t*)(ws + off_packed);

        detect_kernel<<<1, TB, 0, stream>>>((const uint32_t*)ei, flag);
        zero_int_kernel<<<NBUCKET / TB, TB, 0, stream>>>(cursor);
        scatter_sort_kernel<<<NBLK_SS, TB_SS, 0, stream>>>(ei, flag, cursor, packed);
        degdinv_kernel<<<NBUCKET, 512, 0, stream>>>(packed, cursor, x, dinv, za);

        hop_kernel<<<NBUCKET, 512, 0, stream>>>(packed, cursor, za, dinv, zb, 1);
        hop_kernel<<<NBUCKET, 512, 0, stream>>>(packed, cursor, zb, dinv, za, 1);
        hop_kernel<<<NBUCKET, 512, 0, stream>>>(packed, cursor, za, dinv, zb, 1);
        hop_kernel<<<NBUCKET, 512, 0, stream>>>(packed, cursor, zb, dinv, za, 0);

        pool_kernel<<<N_GRAPHS, TB, 0, stream>>>(za, W, b, out);
    } else {
        // Fallback: push-based with atomics.
        int*   flag = (int*)ws;
        float* dinv = (float*)(ws + 256);
        float* za   = (float*)(ws + 256 + MB4);
        float* zb   = (float*)(ws + 256 + 2 * MB4);
        int*   deg  = (int*)(ws + 256 + 3 * MB4);

        detect_kernel<<<1, TB, 0, stream>>>((const uint32_t*)ei, flag);
        zero_int_kernel<<<N_NODES / TB, TB, 0, stream>>>(deg);
        count_kernel<<<N_EDGES / TB, TB, 0, stream>>>(ei, flag, deg);
        dinv_kernel<<<N_NODES / TB, TB, 0, stream>>>(deg, dinv);

        prep_first2_kernel<<<N_NODES / TB, TB, 0, stream>>>(x, dinv, za, zb);
        push_kernel<<<N_EDGES / TB, TB, 0, stream>>>(ei, flag, za, zb);
        for (int h = 1; h < K_HOPS; ++h) {
            prep_mid_kernel<<<N_NODES / TB, TB, 0, stream>>>(dinv, za, zb);
            push_kernel<<<N_EDGES / TB, TB, 0, stream>>>(ei, flag, za, zb);
        }
        final_scale_kernel<<<N_NODES / TB, TB, 0, stream>>>(dinv, zb, za);
        pool_kernel<<<N_GRAPHS, TB, 0, stream>>>(za, W, b, out);
    }
}

// Round 9
// 654.655 us; speedup vs baseline: 1.0361x; 1.0361x over previous
//
#include <hip/hip_runtime.h>
#include <stdint.h>

#define N_NODES  (1u << 20)      // 1048576
#define N_EDGES  (1u << 24)      // 16777216
#define N_GRAPHS 64
#define CHUNK    (N_NODES / N_GRAPHS)  // 16384
#define K_HOPS   4

#define NBUCKET  1024            // column buckets
#define CPB      1024            // cols per bucket
#define CAP      18432           // slots per bucket region (λ=16384, +16σ)

#define NBLK_SS  512             // scatter-sort blocks
#define TB_SS    1024            // scatter-sort threads
#define EPT      32              // edges per thread
#define EPB_SS   (TB_SS * EPT)   // 32768 edges per block

typedef uint32_t u32x4 __attribute__((ext_vector_type(4)));
typedef unsigned long long u64x2 __attribute__((ext_vector_type(2)));

__device__ __forceinline__ u32x4 nt_load_u32x4(const uint32_t* p) {
    return __builtin_nontemporal_load((const u32x4*)p);
}
__device__ __forceinline__ u64x2 nt_load_u64x2(const unsigned long long* p) {
    return __builtin_nontemporal_load((const u64x2*)p);
}

// ---------------------------------------------------------------------------
// Fused: edge-dtype detect (int64 has all-zero odd u32 words for idx < 2^20)
// + zero cursor[NBUCKET] + zero gsum[N_GRAPHS]. Single block.
__global__ void detect_zero_kernel(const uint32_t* __restrict__ ei, int* __restrict__ flag,
                                   int* __restrict__ cursor, float* __restrict__ gsum) {
    __shared__ int any_nz;
    if (threadIdx.x == 0) any_nz = 0;
    __syncthreads();
    int nz = 0;
    for (int i = threadIdx.x; i < 32768; i += blockDim.x)
        nz |= (ei[2 * i + 1] != 0u);
    if (nz) atomicOr(&any_nz, 1);
    for (int i = threadIdx.x; i < NBUCKET; i += blockDim.x) cursor[i] = 0;
    for (int i = threadIdx.x; i < N_GRAPHS; i += blockDim.x) gsum[i] = 0.0f;
    __syncthreads();
    if (threadIdx.x == 0) flag[0] = any_nz ? 0 : 1;
}

// ---------------------------------------------------------------------------
// Per-block LDS counting sort by bucket, then coalesced run write-out.
__global__ __launch_bounds__(TB_SS, 4)
void scatter_sort_kernel(const void* __restrict__ ei, const int* __restrict__ flag,
                         int* __restrict__ cursor, uint32_t* __restrict__ packed) {
    __shared__ uint32_t sorted[EPB_SS];   // 128 KB
    __shared__ int h[NBUCKET];            // 4 KB
    __shared__ int o[NBUCKET];            // 4 KB (scan, then bumped by scatter)
    __shared__ int ostart[NBUCKET];       // 4 KB (stable run starts)
    __shared__ int gbase[NBUCKET];        // 4 KB
    int blk = blockIdx.x, tid = threadIdx.x;
    h[tid] = 0;
    __syncthreads();
    size_t base = (size_t)blk * EPB_SS;
    int is64 = flag[0];
    uint32_t c_[EPT];

    // Phase A: load cols (non-temporal stream), histogram buckets.
    if (is64) {
        const unsigned long long* cp = (const unsigned long long*)ei + N_EDGES + base;
        #pragma unroll
        for (int it = 0; it < EPT / 4; ++it) {
            size_t i = (size_t)it * (TB_SS * 4) + (size_t)tid * 4;
            u64x2 a = nt_load_u64x2(cp + i);
            u64x2 b2 = nt_load_u64x2(cp + i + 2);
            c_[it * 4 + 0] = (uint32_t)a.x;  c_[it * 4 + 1] = (uint32_t)a.y;
            c_[it * 4 + 2] = (uint32_t)b2.x; c_[it * 4 + 3] = (uint32_t)b2.y;
            atomicAdd(&h[c_[it * 4 + 0] >> 10], 1);
            atomicAdd(&h[c_[it * 4 + 1] >> 10], 1);
            atomicAdd(&h[c_[it * 4 + 2] >> 10], 1);
            atomicAdd(&h[c_[it * 4 + 3] >> 10], 1);
        }
    } else {
        const uint32_t* cp = (const uint32_t*)ei + N_EDGES + base;
        #pragma unroll
        for (int it = 0; it < EPT / 4; ++it) {
            size_t i = (size_t)it * (TB_SS * 4) + (size_t)tid * 4;
            u32x4 a = nt_load_u32x4(cp + i);
            c_[it * 4 + 0] = a.x; c_[it * 4 + 1] = a.y;
            c_[it * 4 + 2] = a.z; c_[it * 4 + 3] = a.w;
            atomicAdd(&h[a.x >> 10], 1);
            atomicAdd(&h[a.y >> 10], 1);
            atomicAdd(&h[a.z >> 10], 1);
            atomicAdd(&h[a.w >> 10], 1);
        }
    }
    __syncthreads();

    // Phase B: wave 0 exclusive-scans h[1024] -> o/ostart.
    if (tid < 64) {
        int b16 = tid * 16;
        int s = 0;
        #pragma unroll
        for (int j = 0; j < 16; ++j) s += h[b16 + j];
        int v = s;
        #pragma unroll
        for (int off = 1; off < 64; off <<= 1) {
            int up = __shfl_up(v, off, 64);
            if (tid >= off) v += up;
        }
        int run = v - s;  // exclusive
        #pragma unroll
        for (int j = 0; j < 16; ++j) {
            o[b16 + j] = run;
            ostart[b16 + j] = run;
            run += h[b16 + j];
        }
    }
    __syncthreads();

    // Per-bucket global reserve (1 atomic per bucket per block).
    gbase[tid] = atomicAdd(&cursor[tid], h[tid]);

    // Phase C: load rows (non-temporal), scatter packed entries into LDS.
    if (is64) {
        const unsigned long long* rp = (const unsigned long long*)ei + base;
        #pragma unroll
        for (int it = 0; it < EPT / 4; ++it) {
            size_t i = (size_t)it * (TB_SS * 4) + (size_t)tid * 4;
            u64x2 a = nt_load_u64x2(rp + i);
            u64x2 b2 = nt_load_u64x2(rp + i + 2);
            uint32_t r0 = (uint32_t)a.x, r1 = (uint32_t)a.y;
            uint32_t r2 = (uint32_t)b2.x, r3 = (uint32_t)b2.y;
            { uint32_t c = c_[it * 4 + 0]; int pos = atomicAdd(&o[c >> 10], 1); sorted[pos] = (r0 << 10) | (c & 1023u); }
            { uint32_t c = c_[it * 4 + 1]; int pos = atomicAdd(&o[c >> 10], 1); sorted[pos] = (r1 << 10) | (c & 1023u); }
            { uint32_t c = c_[it * 4 + 2]; int pos = atomicAdd(&o[c >> 10], 1); sorted[pos] = (r2 << 10) | (c & 1023u); }
            { uint32_t c = c_[it * 4 + 3]; int pos = atomicAdd(&o[c >> 10], 1); sorted[pos] = (r3 << 10) | (c & 1023u); }
        }
    } else {
        const uint32_t* rp = (const uint32_t*)ei + base;
        #pragma unroll
        for (int it = 0; it < EPT / 4; ++it) {
            size_t i = (size_t)it * (TB_SS * 4) + (size_t)tid * 4;
            u32x4 a = nt_load_u32x4(rp + i);
            { uint32_t c = c_[it * 4 + 0]; int pos = atomicAdd(&o[c >> 10], 1); sorted[pos] = (a.x << 10) | (c & 1023u); }
            { uint32_t c = c_[it * 4 + 1]; int pos = atomicAdd(&o[c >> 10], 1); sorted[pos] = (a.y << 10) | (c & 1023u); }
            { uint32_t c = c_[it * 4 + 2]; int pos = atomicAdd(&o[c >> 10], 1); sorted[pos] = (a.z << 10) | (c & 1023u); }
            { uint32_t c = c_[it * 4 + 3]; int pos = atomicAdd(&o[c >> 10], 1); sorted[pos] = (a.w << 10) | (c & 1023u); }
        }
    }
    __syncthreads();

    // Phase D: write-out. Wave w copies buckets [w*64, w*64+64); runs contiguous.
    int wave = tid >> 6, lane = tid & 63;
    for (int k = 0; k < NBUCKET / 16; ++k) {
        int b = wave * (NBUCKET / 16) + k;
        int st = ostart[b];
        int len = o[b] - st;
        int gb = gbase[b];
        if (gb + len > CAP) len = CAP - gb > 0 ? CAP - gb : 0;
        uint32_t* dst = packed + (size_t)b * CAP + gb;
        for (int j = lane; j < len; j += 64)
            dst[j] = sorted[st + j];
    }
}

// ---------------------------------------------------------------------------
// Per-bucket degree -> dinv, fused with z0 = dinv * x. nt streaming reads.
__global__ __launch_bounds__(512)
void degdinv_kernel(const uint32_t* __restrict__ packed, const int* __restrict__ cursor,
                    const float* __restrict__ x,
                    float* __restrict__ dinv, float* __restrict__ z) {
    __shared__ int h[CPB];
    int b = blockIdx.x, tid = threadIdx.x;
    for (int l = tid; l < CPB; l += 512) h[l] = 0;
    __syncthreads();
    int cnt = cursor[b]; if (cnt > CAP) cnt = CAP;
    const uint32_t* seg = packed + (size_t)b * CAP;
    int nq = cnt >> 2;
    for (int g = tid; g < nq; g += 512) {
        u32x4 v = nt_load_u32x4(seg + g * 4);
        atomicAdd(&h[v.x & 1023u], 1);
        atomicAdd(&h[v.y & 1023u], 1);
        atomicAdd(&h[v.z & 1023u], 1);
        atomicAdd(&h[v.w & 1023u], 1);
    }
    int t = (nq << 2) + tid;
    if (t < cnt) atomicAdd(&h[seg[t] & 1023u], 1);
    __syncthreads();
    for (int l = tid; l < CPB; l += 512) {
        int v = b * CPB + l;
        float d = (float)(1.0 / sqrt((double)(h[l] + 1)));  // +1 self loop
        dinv[v] = d;
        z[v] = d * x[v];
    }
}

// ---------------------------------------------------------------------------
// Bucketed mid hop: LDS accumulate z[row] per local col (nt on packed stream),
// then zout[v] = d^2 * (z[v] + facc).
__global__ __launch_bounds__(512)
void hop_kernel(const uint32_t* __restrict__ packed, const int* __restrict__ cursor,
                const float* __restrict__ z, const float* __restrict__ dinv,
                float* __restrict__ out) {
    __shared__ float facc[CPB];
    int b = blockIdx.x, tid = threadIdx.x;
    for (int l = tid; l < CPB; l += 512) facc[l] = 0.0f;
    __syncthreads();
    int cnt = cursor[b]; if (cnt > CAP) cnt = CAP;
    const uint32_t* seg = packed + (size_t)b * CAP;
    int nq = cnt >> 2;
    for (int g = tid; g < nq; g += 512) {
        u32x4 v = nt_load_u32x4(seg + g * 4);
        float z0 = z[v.x >> 10];
        float z1 = z[v.y >> 10];
        float z2 = z[v.z >> 10];
        float z3 = z[v.w >> 10];
        atomicAdd(&facc[v.x & 1023u], z0);
        atomicAdd(&facc[v.y & 1023u], z1);
        atomicAdd(&facc[v.z & 1023u], z2);
        atomicAdd(&facc[v.w & 1023u], z3);
    }
    int t = (nq << 2) + tid;
    if (t < cnt) { uint32_t p = seg[t]; atomicAdd(&facc[p & 1023u], z[p >> 10]); }
    __syncthreads();
    for (int l = tid; l < CPB; l += 512) {
        int v = b * CPB + l;
        float tt = z[v] + facc[l];
        float d = dinv[v];
        out[v] = d * d * tt;
    }
}

// ---------------------------------------------------------------------------
// Final hop fused with pooling: compute xf[v] = d*(z[v]+facc) and reduce the
// block's 1024 values into one float atomicAdd into gsum[graph]. No xf write.
__global__ __launch_bounds__(512)
void hop_final_kernel(const uint32_t* __restrict__ packed, const int* __restrict__ cursor,
                      const float* __restrict__ z, const float* __restrict__ dinv,
                      float* __restrict__ gsum) {
    __shared__ float facc[CPB];
    __shared__ double sdata[8];
    int b = blockIdx.x, tid = threadIdx.x;
    for (int l = tid; l < CPB; l += 512) facc[l] = 0.0f;
    __syncthreads();
    int cnt = cursor[b]; if (cnt > CAP) cnt = CAP;
    const uint32_t* seg = packed + (size_t)b * CAP;
    int nq = cnt >> 2;
    for (int g = tid; g < nq; g += 512) {
        u32x4 v = nt_load_u32x4(seg + g * 4);
        float z0 = z[v.x >> 10];
        float z1 = z[v.y >> 10];
        float z2 = z[v.z >> 10];
        float z3 = z[v.w >> 10];
        atomicAdd(&facc[v.x & 1023u], z0);
        atomicAdd(&facc[v.y & 1023u], z1);
        atomicAdd(&facc[v.z & 1023u], z2);
        atomicAdd(&facc[v.w & 1023u], z3);
    }
    int t = (nq << 2) + tid;
    if (t < cnt) { uint32_t p = seg[t]; atomicAdd(&facc[p & 1023u], z[p >> 10]); }
    __syncthreads();
    double s = 0.0;
    for (int l = tid; l < CPB; l += 512) {
        int v = b * CPB + l;
        s += (double)(dinv[v] * (z[v] + facc[l]));
    }
    #pragma unroll
    for (int off = 32; off > 0; off >>= 1) s += __shfl_down(s, off, 64);
    int wave = tid >> 6, lane = tid & 63;
    if (lane == 0) sdata[wave] = s;
    __syncthreads();
    if (tid == 0) {
        double tot = 0.0;
        #pragma unroll
        for (int w = 0; w < 8; ++w) tot += sdata[w];
        atomicAdd(&gsum[b >> 4], (float)tot);   // 16 buckets per graph chunk
    }
}

// out[g] = W * gsum[g]/CHUNK + b
__global__ void finalize_kernel(const float* __restrict__ gsum,
                                const float* __restrict__ W, const float* __restrict__ b,
                                float* __restrict__ out) {
    int g = threadIdx.x;
    if (g < N_GRAPHS)
        out[g] = (float)((double)W[0] * ((double)gsum[g] / (double)CHUNK) + (double)b[0]);
}

// ---------------- fallback (push, atomics) for small ws ---------------------
__global__ void detect_kernel(const uint32_t* __restrict__ ei, int* __restrict__ flag) {
    __shared__ int any_nz;
    if (threadIdx.x == 0) any_nz = 0;
    __syncthreads();
    int nz = 0;
    for (int i = threadIdx.x; i < 32768; i += blockDim.x)
        nz |= (ei[2 * i + 1] != 0u);
    if (nz) atomicOr(&any_nz, 1);
    __syncthreads();
    if (threadIdx.x == 0) flag[0] = any_nz ? 0 : 1;
}

__global__ void zero_int_kernel(int* __restrict__ p) {
    int i = blockIdx.x * blockDim.x + threadIdx.x;
    p[i] = 0;
}

__device__ __forceinline__ int load_idx(const void* ei, int is64, size_t pos) {
    if (is64) return (int)((const unsigned long long*)ei)[pos];
    return ((const int*)ei)[pos];
}

__global__ void count_kernel(const void* __restrict__ ei, const int* __restrict__ flag,
                             int* __restrict__ deg) {
    int e = blockIdx.x * blockDim.x + threadIdx.x;
    int c = load_idx(ei, flag[0], (size_t)N_EDGES + (size_t)e);
    atomicAdd(&deg[c], 1);
}

__global__ void dinv_kernel(const int* __restrict__ deg, float* __restrict__ dinv) {
    int v = blockIdx.x * blockDim.x + threadIdx.x;
    dinv[v] = (float)(1.0 / sqrt((double)(deg[v] + 1)));
}

__global__ void prep_first2_kernel(const float* __restrict__ x, const float* __restrict__ dinv,
                                   float* __restrict__ z, float* __restrict__ acc) {
    int v = blockIdx.x * blockDim.x + threadIdx.x;
    float t = dinv[v] * x[v];
    z[v] = t;
    acc[v] = t;
}

__global__ void prep_mid_kernel(const float* __restrict__ dinv,
                                float* __restrict__ z, float* __restrict__ acc) {
    int v = blockIdx.x * blockDim.x + threadIdx.x;
    float d = dinv[v];
    float t = d * d * acc[v];
    z[v] = t;
    acc[v] = t;
}

__global__ void push_kernel(const void* __restrict__ ei, const int* __restrict__ flag,
                            const float* __restrict__ z, float* __restrict__ acc) {
    int e = blockIdx.x * blockDim.x + threadIdx.x;
    int is64 = flag[0];
    int r, c;
    if (is64) {
        const unsigned long long* p = (const unsigned long long*)ei;
        r = (int)p[e];
        c = (int)p[(size_t)N_EDGES + (size_t)e];
    } else {
        const int* p = (const int*)ei;
        r = p[e];
        c = p[(size_t)N_EDGES + (size_t)e];
    }
    __hip_atomic_fetch_add(&acc[c], z[r], __ATOMIC_RELAXED, __HIP_MEMORY_SCOPE_AGENT);
}

__global__ void final_scale_kernel(const float* __restrict__ dinv,
                                   const float* __restrict__ acc, float* __restrict__ xf) {
    int v = blockIdx.x * blockDim.x + threadIdx.x;
    xf[v] = dinv[v] * acc[v];
}

__global__ void pool_kernel(const float* __restrict__ xf,
                            const float* __restrict__ W, const float* __restrict__ b,
                            float* __restrict__ out) {
    __shared__ double sdata[256];
    int g = blockIdx.x;
    int base = g * CHUNK;
    double s = 0.0;
    for (int i = threadIdx.x; i < CHUNK; i += 256) s += (double)xf[base + i];
    sdata[threadIdx.x] = s;
    __syncthreads();
    for (int off = 128; off > 0; off >>= 1) {
        if (threadIdx.x < off) sdata[threadIdx.x] += sdata[threadIdx.x + off];
        __syncthreads();
    }
    if (threadIdx.x == 0)
        out[g] = (float)((double)W[0] * (sdata[0] / (double)CHUNK) + (double)b[0]);
}

extern "C" void kernel_launch(void* const* d_in, const int* in_sizes, int n_in,
                              void* d_out, int out_size, void* d_ws, size_t ws_size,
                              hipStream_t stream) {
    const float* x = (const float*)d_in[0];
    const void*  ei = d_in[1];
    const float* W = (const float*)d_in[2];
    const float* b = (const float*)d_in[3];
    float* out = (float*)d_out;

    char* ws = (char*)d_ws;
    const size_t MB4 = 4ull << 20;
    size_t off_flag   = 0;                                // 256 B
    size_t off_cursor = 256;                              // 4 KB
    size_t off_gsum   = off_cursor + NBUCKET * 4;         // 256 B
    size_t off_dinv   = off_gsum + 256;                   // 4 MB
    size_t off_za     = off_dinv + MB4;                   // 4 MB
    size_t off_zb     = off_za + MB4;                     // 4 MB
    size_t off_packed = off_zb + MB4;                     // 72 MB
    size_t needed     = off_packed + (size_t)NBUCKET * CAP * 4;

    const int TB = 256;

    if (ws_size >= needed) {
        int*      flag   = (int*)(ws + off_flag);
        int*      cursor = (int*)(ws + off_cursor);
        float*    gsum   = (float*)(ws + off_gsum);
        float*    dinv   = (float*)(ws + off_dinv);
        float*    za     = (float*)(ws + off_za);
        float*    zb     = (float*)(ws + off_zb);
        uint32_t* packed = (uint32_t*)(ws + off_packed);

        detect_zero_kernel<<<1, TB, 0, stream>>>((const uint32_t*)ei, flag, cursor, gsum);
        scatter_sort_kernel<<<NBLK_SS, TB_SS, 0, stream>>>(ei, flag, cursor, packed);
        degdinv_kernel<<<NBUCKET, 512, 0, stream>>>(packed, cursor, x, dinv, za);

        hop_kernel<<<NBUCKET, 512, 0, stream>>>(packed, cursor, za, dinv, zb);
        hop_kernel<<<NBUCKET, 512, 0, stream>>>(packed, cursor, zb, dinv, za);
        hop_kernel<<<NBUCKET, 512, 0, stream>>>(packed, cursor, za, dinv, zb);
        hop_final_kernel<<<NBUCKET, 512, 0, stream>>>(packed, cursor, zb, dinv, gsum);

        finalize_kernel<<<1, 64, 0, stream>>>(gsum, W, b, out);
    } else {
        // Fallback: push-based with atomics.
        int*   flag = (int*)ws;
        float* dinv = (float*)(ws + 256);
        float* za   = (float*)(ws + 256 + MB4);
        float* zb   = (float*)(ws + 256 + 2 * MB4);
        int*   deg  = (int*)(ws + 256 + 3 * MB4);

        detect_kernel<<<1, TB, 0, stream>>>((const uint32_t*)ei, flag);
        zero_int_kernel<<<N_NODES / TB, TB, 0, stream>>>(deg);
        count_kernel<<<N_EDGES / TB, TB, 0, stream>>>(ei, flag, deg);
        dinv_kernel<<<N_NODES / TB, TB, 0, stream>>>(deg, dinv);

        prep_first2_kernel<<<N_NODES / TB, TB, 0, stream>>>(x, dinv, za, zb);
        push_kernel<<<N_EDGES / TB, TB, 0, stream>>>(ei, flag, za, zb);
        for (int h = 1; h < K_HOPS; ++h) {
            prep_mid_kernel<<<N_NODES / TB, TB, 0, stream>>>(dinv, za, zb);
            push_kernel<<<N_EDGES / TB, TB, 0, stream>>>(ei, flag, za, zb);
        }
        final_scale_kernel<<<N_NODES / TB, TB, 0, stream>>>(dinv, zb, za);
        pool_kernel<<<N_GRAPHS, TB, 0, stream>>>(za, W, b, out);
    }
}

// Round 10
// 625.803 us; speedup vs baseline: 1.0839x; 1.0461x over previous
//
#include <hip/hip_runtime.h>
#include <stdint.h>

#define N_NODES  (1u << 20)      // 1048576
#define N_EDGES  (1u << 24)      // 16777216
#define N_GRAPHS 64
#define CHUNK    (N_NODES / N_GRAPHS)  // 16384
#define K_HOPS   4

#define NBUCKET  1024            // column buckets
#define CPB      1024            // cols per bucket
#define CAP      18432           // slots per bucket region (λ=16384, +16σ)

#define NBLK_SS  512             // scatter-sort blocks
#define TB_SS    1024            // scatter-sort threads
#define EPT      32              // edges per thread
#define EPB_SS   (TB_SS * EPT)   // 32768 edges per block

typedef uint32_t u32x4 __attribute__((ext_vector_type(4)));
typedef unsigned long long u64x2 __attribute__((ext_vector_type(2)));

__device__ __forceinline__ u32x4 nt_load_u32x4(const uint32_t* p) {
    return __builtin_nontemporal_load((const u32x4*)p);
}
__device__ __forceinline__ u64x2 nt_load_u64x2(const unsigned long long* p) {
    return __builtin_nontemporal_load((const u64x2*)p);
}

// ---------------------------------------------------------------------------
// Per-block LDS counting sort by bucket, then coalesced run write-out.
// Edge dtype detected per block: 64 sampled odd u32 words of its own slice —
// int64 little-endian (idx < 2^20) has all-zero odd words; int32 has random
// node indices there (P(all 64 zero) ~ (1e-6)^64 = 0).
__global__ __launch_bounds__(TB_SS, 4)
void scatter_sort_kernel(const void* __restrict__ ei,
                         int* __restrict__ cursor, uint32_t* __restrict__ packed) {
    __shared__ uint32_t sorted[EPB_SS];   // 128 KB
    __shared__ int h[NBUCKET];            // 4 KB
    __shared__ int o[NBUCKET];            // 4 KB (scan, then bumped by scatter)
    __shared__ int ostart[NBUCKET];       // 4 KB (stable run starts)
    __shared__ int gbase[NBUCKET];        // 4 KB
    __shared__ int s_is64;
    int blk = blockIdx.x, tid = threadIdx.x;
    h[tid] = 0;
    size_t base = (size_t)blk * EPB_SS;

    // dtype detection: wave 0 samples odd u32 words across this block's slice.
    if (tid < 64) {
        size_t widx = 2 * base + 2 * (size_t)tid * 512 + 1;
        int nz = (((const uint32_t*)ei)[widx] != 0u);
        unsigned long long m = __ballot(nz);
        if (tid == 0) s_is64 = (m == 0ull) ? 1 : 0;
    }
    __syncthreads();
    int is64 = s_is64;
    uint32_t c_[EPT];

    // Phase A: load cols (non-temporal stream), histogram buckets.
    if (is64) {
        const unsigned long long* cp = (const unsigned long long*)ei + N_EDGES + base;
        #pragma unroll
        for (int it = 0; it < EPT / 4; ++it) {
            size_t i = (size_t)it * (TB_SS * 4) + (size_t)tid * 4;
            u64x2 a = nt_load_u64x2(cp + i);
            u64x2 b2 = nt_load_u64x2(cp + i + 2);
            c_[it * 4 + 0] = (uint32_t)a.x;  c_[it * 4 + 1] = (uint32_t)a.y;
            c_[it * 4 + 2] = (uint32_t)b2.x; c_[it * 4 + 3] = (uint32_t)b2.y;
            atomicAdd(&h[c_[it * 4 + 0] >> 10], 1);
            atomicAdd(&h[c_[it * 4 + 1] >> 10], 1);
            atomicAdd(&h[c_[it * 4 + 2] >> 10], 1);
            atomicAdd(&h[c_[it * 4 + 3] >> 10], 1);
        }
    } else {
        const uint32_t* cp = (const uint32_t*)ei + N_EDGES + base;
        #pragma unroll
        for (int it = 0; it < EPT / 4; ++it) {
            size_t i = (size_t)it * (TB_SS * 4) + (size_t)tid * 4;
            u32x4 a = nt_load_u32x4(cp + i);
            c_[it * 4 + 0] = a.x; c_[it * 4 + 1] = a.y;
            c_[it * 4 + 2] = a.z; c_[it * 4 + 3] = a.w;
            atomicAdd(&h[a.x >> 10], 1);
            atomicAdd(&h[a.y >> 10], 1);
            atomicAdd(&h[a.z >> 10], 1);
            atomicAdd(&h[a.w >> 10], 1);
        }
    }
    __syncthreads();

    // Phase B: wave 0 exclusive-scans h[1024] -> o/ostart.
    if (tid < 64) {
        int b16 = tid * 16;
        int s = 0;
        #pragma unroll
        for (int j = 0; j < 16; ++j) s += h[b16 + j];
        int v = s;
        #pragma unroll
        for (int off = 1; off < 64; off <<= 1) {
            int up = __shfl_up(v, off, 64);
            if (tid >= off) v += up;
        }
        int run = v - s;  // exclusive
        #pragma unroll
        for (int j = 0; j < 16; ++j) {
            o[b16 + j] = run;
            ostart[b16 + j] = run;
            run += h[b16 + j];
        }
    }
    __syncthreads();

    // Per-bucket global reserve (1 atomic per bucket per block).
    gbase[tid] = atomicAdd(&cursor[tid], h[tid]);

    // Phase C: load rows (non-temporal), scatter packed entries into LDS.
    if (is64) {
        const unsigned long long* rp = (const unsigned long long*)ei + base;
        #pragma unroll
        for (int it = 0; it < EPT / 4; ++it) {
            size_t i = (size_t)it * (TB_SS * 4) + (size_t)tid * 4;
            u64x2 a = nt_load_u64x2(rp + i);
            u64x2 b2 = nt_load_u64x2(rp + i + 2);
            uint32_t r0 = (uint32_t)a.x, r1 = (uint32_t)a.y;
            uint32_t r2 = (uint32_t)b2.x, r3 = (uint32_t)b2.y;
            { uint32_t c = c_[it * 4 + 0]; int pos = atomicAdd(&o[c >> 10], 1); sorted[pos] = (r0 << 10) | (c & 1023u); }
            { uint32_t c = c_[it * 4 + 1]; int pos = atomicAdd(&o[c >> 10], 1); sorted[pos] = (r1 << 10) | (c & 1023u); }
            { uint32_t c = c_[it * 4 + 2]; int pos = atomicAdd(&o[c >> 10], 1); sorted[pos] = (r2 << 10) | (c & 1023u); }
            { uint32_t c = c_[it * 4 + 3]; int pos = atomicAdd(&o[c >> 10], 1); sorted[pos] = (r3 << 10) | (c & 1023u); }
        }
    } else {
        const uint32_t* rp = (const uint32_t*)ei + base;
        #pragma unroll
        for (int it = 0; it < EPT / 4; ++it) {
            size_t i = (size_t)it * (TB_SS * 4) + (size_t)tid * 4;
            u32x4 a = nt_load_u32x4(rp + i);
            { uint32_t c = c_[it * 4 + 0]; int pos = atomicAdd(&o[c >> 10], 1); sorted[pos] = (a.x << 10) | (c & 1023u); }
            { uint32_t c = c_[it * 4 + 1]; int pos = atomicAdd(&o[c >> 10], 1); sorted[pos] = (a.y << 10) | (c & 1023u); }
            { uint32_t c = c_[it * 4 + 2]; int pos = atomicAdd(&o[c >> 10], 1); sorted[pos] = (a.z << 10) | (c & 1023u); }
            { uint32_t c = c_[it * 4 + 3]; int pos = atomicAdd(&o[c >> 10], 1); sorted[pos] = (a.w << 10) | (c & 1023u); }
        }
    }
    __syncthreads();

    // Phase D: write-out. Wave w copies buckets [w*64, w*64+64); runs contiguous.
    int wave = tid >> 6, lane = tid & 63;
    for (int k = 0; k < NBUCKET / 16; ++k) {
        int b = wave * (NBUCKET / 16) + k;
        int st = ostart[b];
        int len = o[b] - st;
        int gb = gbase[b];
        if (gb + len > CAP) len = CAP - gb > 0 ? CAP - gb : 0;
        uint32_t* dst = packed + (size_t)b * CAP + gb;
        for (int j = lane; j < len; j += 64)
            dst[j] = sorted[st + j];
    }
}

// ---------------------------------------------------------------------------
// Per-bucket degree -> dinv, fused with z0 = dinv * x. nt streaming reads.
__global__ __launch_bounds__(512)
void degdinv_kernel(const uint32_t* __restrict__ packed, const int* __restrict__ cursor,
                    const float* __restrict__ x,
                    float* __restrict__ dinv, float* __restrict__ z) {
    __shared__ int h[CPB];
    int b = blockIdx.x, tid = threadIdx.x;
    for (int l = tid; l < CPB; l += 512) h[l] = 0;
    __syncthreads();
    int cnt = cursor[b]; if (cnt > CAP) cnt = CAP;
    const uint32_t* seg = packed + (size_t)b * CAP;
    int nq = cnt >> 2;
    for (int g = tid; g < nq; g += 512) {
        u32x4 v = nt_load_u32x4(seg + g * 4);
        atomicAdd(&h[v.x & 1023u], 1);
        atomicAdd(&h[v.y & 1023u], 1);
        atomicAdd(&h[v.z & 1023u], 1);
        atomicAdd(&h[v.w & 1023u], 1);
    }
    int t = (nq << 2) + tid;
    if (t < cnt) atomicAdd(&h[seg[t] & 1023u], 1);
    __syncthreads();
    for (int l = tid; l < CPB; l += 512) {
        int v = b * CPB + l;
        float d = (float)(1.0 / sqrt((double)(h[l] + 1)));  // +1 self loop
        dinv[v] = d;
        z[v] = d * x[v];
    }
}

// ---------------------------------------------------------------------------
// Bucketed mid hop: LDS accumulate z[row] per local col (nt on packed stream),
// then zout[v] = d^2 * (z[v] + facc).
__global__ __launch_bounds__(512)
void hop_kernel(const uint32_t* __restrict__ packed, const int* __restrict__ cursor,
                const float* __restrict__ z, const float* __restrict__ dinv,
                float* __restrict__ out) {
    __shared__ float facc[CPB];
    int b = blockIdx.x, tid = threadIdx.x;
    for (int l = tid; l < CPB; l += 512) facc[l] = 0.0f;
    __syncthreads();
    int cnt = cursor[b]; if (cnt > CAP) cnt = CAP;
    const uint32_t* seg = packed + (size_t)b * CAP;
    int nq = cnt >> 2;
    for (int g = tid; g < nq; g += 512) {
        u32x4 v = nt_load_u32x4(seg + g * 4);
        float z0 = z[v.x >> 10];
        float z1 = z[v.y >> 10];
        float z2 = z[v.z >> 10];
        float z3 = z[v.w >> 10];
        atomicAdd(&facc[v.x & 1023u], z0);
        atomicAdd(&facc[v.y & 1023u], z1);
        atomicAdd(&facc[v.z & 1023u], z2);
        atomicAdd(&facc[v.w & 1023u], z3);
    }
    int t = (nq << 2) + tid;
    if (t < cnt) { uint32_t p = seg[t]; atomicAdd(&facc[p & 1023u], z[p >> 10]); }
    __syncthreads();
    for (int l = tid; l < CPB; l += 512) {
        int v = b * CPB + l;
        float tt = z[v] + facc[l];
        float d = dinv[v];
        out[v] = d * d * tt;
    }
}

// ---------------------------------------------------------------------------
// Final hop fused with pooling: xf[v] = d*(z[v]+facc) reduced per block into
// one float atomicAdd into gsum[graph]. No xf write.
__global__ __launch_bounds__(512)
void hop_final_kernel(const uint32_t* __restrict__ packed, const int* __restrict__ cursor,
                      const float* __restrict__ z, const float* __restrict__ dinv,
                      float* __restrict__ gsum) {
    __shared__ float facc[CPB];
    __shared__ double sdata[8];
    int b = blockIdx.x, tid = threadIdx.x;
    for (int l = tid; l < CPB; l += 512) facc[l] = 0.0f;
    __syncthreads();
    int cnt = cursor[b]; if (cnt > CAP) cnt = CAP;
    const uint32_t* seg = packed + (size_t)b * CAP;
    int nq = cnt >> 2;
    for (int g = tid; g < nq; g += 512) {
        u32x4 v = nt_load_u32x4(seg + g * 4);
        float z0 = z[v.x >> 10];
        float z1 = z[v.y >> 10];
        float z2 = z[v.z >> 10];
        float z3 = z[v.w >> 10];
        atomicAdd(&facc[v.x & 1023u], z0);
        atomicAdd(&facc[v.y & 1023u], z1);
        atomicAdd(&facc[v.z & 1023u], z2);
        atomicAdd(&facc[v.w & 1023u], z3);
    }
    int t = (nq << 2) + tid;
    if (t < cnt) { uint32_t p = seg[t]; atomicAdd(&facc[p & 1023u], z[p >> 10]); }
    __syncthreads();
    double s = 0.0;
    for (int l = tid; l < CPB; l += 512) {
        int v = b * CPB + l;
        s += (double)(dinv[v] * (z[v] + facc[l]));
    }
    #pragma unroll
    for (int off = 32; off > 0; off >>= 1) s += __shfl_down(s, off, 64);
    int wave = tid >> 6, lane = tid & 63;
    if (lane == 0) sdata[wave] = s;
    __syncthreads();
    if (tid == 0) {
        double tot = 0.0;
        #pragma unroll
        for (int w = 0; w < 8; ++w) tot += sdata[w];
        atomicAdd(&gsum[b >> 4], (float)tot);   // 16 buckets per graph chunk
    }
}

// out[g] = W * gsum[g]/CHUNK + b
__global__ void finalize_kernel(const float* __restrict__ gsum,
                                const float* __restrict__ W, const float* __restrict__ b,
                                float* __restrict__ out) {
    int g = threadIdx.x;
    if (g < N_GRAPHS)
        out[g] = (float)((double)W[0] * ((double)gsum[g] / (double)CHUNK) + (double)b[0]);
}

// ---------------- fallback (push, atomics) for small ws ---------------------
__global__ void detect_kernel(const uint32_t* __restrict__ ei, int* __restrict__ flag) {
    __shared__ int any_nz;
    if (threadIdx.x == 0) any_nz = 0;
    __syncthreads();
    int nz = 0;
    for (int i = threadIdx.x; i < 32768; i += blockDim.x)
        nz |= (ei[2 * i + 1] != 0u);
    if (nz) atomicOr(&any_nz, 1);
    __syncthreads();
    if (threadIdx.x == 0) flag[0] = any_nz ? 0 : 1;
}

__global__ void zero_int_kernel(int* __restrict__ p) {
    int i = blockIdx.x * blockDim.x + threadIdx.x;
    p[i] = 0;
}

__device__ __forceinline__ int load_idx(const void* ei, int is64, size_t pos) {
    if (is64) return (int)((const unsigned long long*)ei)[pos];
    return ((const int*)ei)[pos];
}

__global__ void count_kernel(const void* __restrict__ ei, const int* __restrict__ flag,
                             int* __restrict__ deg) {
    int e = blockIdx.x * blockDim.x + threadIdx.x;
    int c = load_idx(ei, flag[0], (size_t)N_EDGES + (size_t)e);
    atomicAdd(&deg[c], 1);
}

__global__ void dinv_kernel(const int* __restrict__ deg, float* __restrict__ dinv) {
    int v = blockIdx.x * blockDim.x + threadIdx.x;
    dinv[v] = (float)(1.0 / sqrt((double)(deg[v] + 1)));
}

__global__ void prep_first2_kernel(const float* __restrict__ x, const float* __restrict__ dinv,
                                   float* __restrict__ z, float* __restrict__ acc) {
    int v = blockIdx.x * blockDim.x + threadIdx.x;
    float t = dinv[v] * x[v];
    z[v] = t;
    acc[v] = t;
}

__global__ void prep_mid_kernel(const float* __restrict__ dinv,
                                float* __restrict__ z, float* __restrict__ acc) {
    int v = blockIdx.x * blockDim.x + threadIdx.x;
    float d = dinv[v];
    float t = d * d * acc[v];
    z[v] = t;
    acc[v] = t;
}

__global__ void push_kernel(const void* __restrict__ ei, const int* __restrict__ flag,
                            const float* __restrict__ z, float* __restrict__ acc) {
    int e = blockIdx.x * blockDim.x + threadIdx.x;
    int is64 = flag[0];
    int r, c;
    if (is64) {
        const unsigned long long* p = (const unsigned long long*)ei;
        r = (int)p[e];
        c = (int)p[(size_t)N_EDGES + (size_t)e];
    } else {
        const int* p = (const int*)ei;
        r = p[e];
        c = p[(size_t)N_EDGES + (size_t)e];
    }
    __hip_atomic_fetch_add(&acc[c], z[r], __ATOMIC_RELAXED, __HIP_MEMORY_SCOPE_AGENT);
}

__global__ void final_scale_kernel(const float* __restrict__ dinv,
                                   const float* __restrict__ acc, float* __restrict__ xf) {
    int v = blockIdx.x * blockDim.x + threadIdx.x;
    xf[v] = dinv[v] * acc[v];
}

__global__ void pool_kernel(const float* __restrict__ xf,
                            const float* __restrict__ W, const float* __restrict__ b,
                            float* __restrict__ out) {
    __shared__ double sdata[256];
    int g = blockIdx.x;
    int base = g * CHUNK;
    double s = 0.0;
    for (int i = threadIdx.x; i < CHUNK; i += 256) s += (double)xf[base + i];
    sdata[threadIdx.x] = s;
    __syncthreads();
    for (int off = 128; off > 0; off >>= 1) {
        if (threadIdx.x < off) sdata[threadIdx.x] += sdata[threadIdx.x + off];
        __syncthreads();
    }
    if (threadIdx.x == 0)
        out[g] = (float)((double)W[0] * (sdata[0] / (double)CHUNK) + (double)b[0]);
}

extern "C" void kernel_launch(void* const* d_in, const int* in_sizes, int n_in,
                              void* d_out, int out_size, void* d_ws, size_t ws_size,
                              hipStream_t stream) {
    const float* x = (const float*)d_in[0];
    const void*  ei = d_in[1];
    const float* W = (const float*)d_in[2];
    const float* b = (const float*)d_in[3];
    float* out = (float*)d_out;

    char* ws = (char*)d_ws;
    const size_t MB4 = 4ull << 20;
    size_t off_cursor = 0;                                // 4 KB
    size_t off_gsum   = NBUCKET * 4;                      // 256 B
    size_t off_dinv   = off_gsum + 256;                   // 4 MB
    size_t off_za     = off_dinv + MB4;                   // 4 MB
    size_t off_zb     = off_za + MB4;                     // 4 MB
    size_t off_packed = off_zb + MB4;                     // 72 MB
    size_t needed     = off_packed + (size_t)NBUCKET * CAP * 4;

    const int TB = 256;

    if (ws_size >= needed) {
        int*      cursor = (int*)(ws + off_cursor);
        float*    gsum   = (float*)(ws + off_gsum);
        float*    dinv   = (float*)(ws + off_dinv);
        float*    za     = (float*)(ws + off_za);
        float*    zb     = (float*)(ws + off_zb);
        uint32_t* packed = (uint32_t*)(ws + off_packed);

        // zero cursor[1024] + gsum[64] in one async memset (graph-capturable)
        hipMemsetAsync(ws, 0, NBUCKET * 4 + 256, stream);

        scatter_sort_kernel<<<NBLK_SS, TB_SS, 0, stream>>>(ei, cursor, packed);
        degdinv_kernel<<<NBUCKET, 512, 0, stream>>>(packed, cursor, x, dinv, za);

        hop_kernel<<<NBUCKET, 512, 0, stream>>>(packed, cursor, za, dinv, zb);
        hop_kernel<<<NBUCKET, 512, 0, stream>>>(packed, cursor, zb, dinv, za);
        hop_kernel<<<NBUCKET, 512, 0, stream>>>(packed, cursor, za, dinv, zb);
        hop_final_kernel<<<NBUCKET, 512, 0, stream>>>(packed, cursor, zb, dinv, gsum);

        finalize_kernel<<<1, 64, 0, stream>>>(gsum, W, b, out);
    } else {
        // Fallback: push-based with atomics.
        int*   flag = (int*)ws;
        float* dinv = (float*)(ws + 256);
        float* za   = (float*)(ws + 256 + MB4);
        float* zb   = (float*)(ws + 256 + 2 * MB4);
        int*   deg  = (int*)(ws + 256 + 3 * MB4);

        detect_kernel<<<1, TB, 0, stream>>>((const uint32_t*)ei, flag);
        zero_int_kernel<<<N_NODES / TB, TB, 0, stream>>>(deg);
        count_kernel<<<N_EDGES / TB, TB, 0, stream>>>(ei, flag, deg);
        dinv_kernel<<<N_NODES / TB, TB, 0, stream>>>(deg, dinv);

        prep_first2_kernel<<<N_NODES / TB, TB, 0, stream>>>(x, dinv, za, zb);
        push_kernel<<<N_EDGES / TB, TB, 0, stream>>>(ei, flag, za, zb);
        for (int h = 1; h < K_HOPS; ++h) {
            prep_mid_kernel<<<N_NODES / TB, TB, 0, stream>>>(dinv, za, zb);
            push_kernel<<<N_EDGES / TB, TB, 0, stream>>>(ei, flag, za, zb);
        }
        final_scale_kernel<<<N_NODES / TB, TB, 0, stream>>>(dinv, zb, za);
        pool_kernel<<<N_GRAPHS, TB, 0, stream>>>(za, W, b, out);
    }
}